// Round 8
// baseline (526.292 us; speedup 1.0000x reference)
//
#include <hip/hip_runtime.h>

#define TAGS 64
#define MAXT 512
#define NEG  -10000.0f
#define CH   8   // feat-staging chunk: steps per LDS buffer

// Round-14: software-pipeline the argmax over the fv LDS round-trip.
// Accounting (r0/r1/r3/r7): step = issue ~560 cyc + ~300 cyc exposed LDS
// write->read->use chain + dep latency ~ 1330. VALUBusy 35-53% with spare
// SIMD slots => latency-bound, not issue-bound. The 159-instr argmax does
// not feed the recurrence, but in r0's program order it sits where it
// cannot cover the LDS round-trip (reads can't hoist above the aliasing
// fv write). r7's VGPR=96 regression showed the reads serialize further
// when quads can't all be in flight.
// Change (single, structural): after fv[lane]=nf (step t), immediately
// issue step t+1's 16 ds_read_b128 into a DEDICATED fq_pre[16] register
// set (in-order LDS => reads see the new fv), then run step t's argmax
// while they fly. sched_barrier(0) pins {write -> reads -> argmax} and
// {argmax | next-step adds}. Register cost: w4 64 + c4 64 + fq_pre 64 +
// temps ~ 220 VGPR -- free at our fixed 1 wave/SIMD (cap 512 via
// __launch_bounds__(64,1); file supports 4x256/CU).
// Everything else is the verified r0 body: LDS fbuf feat staging, cmp/
// cndmask first-occurrence argmax (283us variant), max3/min3 trees,
// terminal butterfly, lane-0 chase, coalesced writeback.
__global__ __launch_bounds__(64, 1) void crf_viterbi(
    const float* __restrict__ feats,   // [B, T, K]
    const float* __restrict__ weights, // [K, K] (weights[next][prev])
    const int*   __restrict__ lens,    // [B]
    float*       __restrict__ out,     // [B] scores ++ [B*T] paths (as f32)
    int B, int T)
{
    const int b    = blockIdx.x;
    const int lane = threadIdx.x;              // next tag
    const int len  = lens[b];                  // 1..T

    __shared__ float fv[TAGS];
    __shared__ float fbuf[2][CH * TAGS];       // 2 x 2 KB feat staging
    __shared__ unsigned char  bptr[MAXT * TAGS];
    __shared__ unsigned short path[MAXT];
    // ~37.3 KB LDS -> 4 blocks/CU

    // W row for this lane (as float4 quads)
    float4 w4[16];
    #pragma unroll
    for (int i = 0; i < 16; ++i)
        w4[i] = *reinterpret_cast<const float4*>(weights + lane * TAGS + i * 4);
    const float wEnd = weights[1 * TAGS + lane];  // transition into END

    fv[lane] = (lane == 0) ? 0.0f : NEG;          // START = 0

    const float* fb  = feats + (size_t)b * T * TAGS;
    const int    lim = len * TAGS - 4;            // clamp for tail loads

    float nf = NEG;                               // this lane's running fv

#define F3(a, b, c) fmaxf(fmaxf((a), (b)), (c))
#define M3(a, b, c) min(min((a), (b)), (c))

    float4 fq_pre[16];                            // pipelined fv quads

    auto step = [&](int cbuf, int i, int t) {
        const float feat = fbuf[cbuf][i * TAGS + lane];  // early, off-chain
        // c = fv(prefetched) + w   -- c4 distinct from fq_pre (WAR-safe:
        // adds issue before the re-fill reads below)
        float4 c4[16];
        #pragma unroll
        for (int g = 0; g < 16; ++g) {
            c4[g].x = fq_pre[g].x + w4[g].x;
            c4[g].y = fq_pre[g].y + w4[g].y;
            c4[g].z = fq_pre[g].z + w4[g].z;
            c4[g].w = fq_pre[g].w + w4[g].w;
        }
        const float* c = reinterpret_cast<const float*>(c4);

        // value-only max: 3-ary tree (v_max3_f32), depth 4
        float v1[22];
        #pragma unroll
        for (int k = 0; k < 21; ++k) v1[k] = F3(c[3*k], c[3*k+1], c[3*k+2]);
        v1[21] = c[63];
        float v2[8];
        #pragma unroll
        for (int k = 0; k < 7; ++k) v2[k] = F3(v1[3*k], v1[3*k+1], v1[3*k+2]);
        v2[7] = v1[21];
        const float v30 = F3(v2[0], v2[1], v2[2]);
        const float v31 = F3(v2[3], v2[4], v2[5]);
        const float v32 = fmaxf(v2[6], v2[7]);
        const float m   = F3(v30, v31, v32);

        nf = m + feat;                 // emission added after max
        fv[lane] = nf;                 // ds_write: unblocks step t+1

        // issue step t+1's fv reads NOW (in-order LDS => they observe the
        // write above); their ~120+ cyc latency hides under the argmax.
        #pragma unroll
        for (int g = 0; g < 16; ++g)
            fq_pre[g] = *reinterpret_cast<const float4*>(&fv[g * 4]);
        __builtin_amdgcn_sched_barrier(0);   // pin: write -> reads -> argmax

        // first-occurrence argmax (r0-verified cmp/cndmask form)
        unsigned e[64];
        #pragma unroll
        for (int p = 0; p < 64; ++p) e[p] = (c[p] == m) ? (unsigned)p : 64u;
        unsigned u1[22];
        #pragma unroll
        for (int k = 0; k < 21; ++k) u1[k] = M3(e[3*k], e[3*k+1], e[3*k+2]);
        u1[21] = e[63];
        unsigned u2[8];
        #pragma unroll
        for (int k = 0; k < 7; ++k) u2[k] = M3(u1[3*k], u1[3*k+1], u1[3*k+2]);
        u2[7] = u1[21];
        const unsigned u30 = M3(u2[0], u2[1], u2[2]);
        const unsigned u31 = M3(u2[3], u2[4], u2[5]);
        const unsigned u32 = min(u2[6], u2[7]);
        const unsigned idx = M3(u30, u31, u32);

        bptr[t * TAGS + lane] = (unsigned char)idx;
        __builtin_amdgcn_sched_barrier(0);   // keep next step's adds below
    };

    // prologue: stage chunk 0 -> fbuf[0]; issue chunk-1 loads
    {
        int o0 = 4 * lane;        if (o0 > lim) o0 = lim;
        int o1 = 256 + 4 * lane;  if (o1 > lim) o1 = lim;
        *reinterpret_cast<float4*>(&fbuf[0][4 * lane])       = *reinterpret_cast<const float4*>(fb + o0);
        *reinterpret_cast<float4*>(&fbuf[0][256 + 4 * lane]) = *reinterpret_cast<const float4*>(fb + o1);
    }
    float4 n0, n1;
    {
        int o0 = CH * TAGS + 4 * lane;        if (o0 > lim) o0 = lim;
        int o1 = CH * TAGS + 256 + 4 * lane;  if (o1 > lim) o1 = lim;
        n0 = *reinterpret_cast<const float4*>(fb + o0);
        n1 = *reinterpret_cast<const float4*>(fb + o1);
    }
    // initial fv prefetch for step 0 (after the init write; in-order LDS)
    #pragma unroll
    for (int g = 0; g < 16; ++g)
        fq_pre[g] = *reinterpret_cast<const float4*>(&fv[g * 4]);

    int cb = 0;
    const int nfull = len / CH;
    for (int c = 0; c < nfull; ++c) {
        #pragma unroll
        for (int i = 0; i < CH; ++i) step(cb, i, c * CH + i);
        // stage chunk c+1 (loads landed ~8 steps ago), issue chunk c+2
        *reinterpret_cast<float4*>(&fbuf[cb ^ 1][4 * lane])       = n0;
        *reinterpret_cast<float4*>(&fbuf[cb ^ 1][256 + 4 * lane]) = n1;
        {
            int o0 = (c + 2) * CH * TAGS + 4 * lane;        if (o0 > lim) o0 = lim;
            int o1 = (c + 2) * CH * TAGS + 256 + 4 * lane;  if (o1 > lim) o1 = lim;
            n0 = *reinterpret_cast<const float4*>(fb + o0);
            n1 = *reinterpret_cast<const float4*>(fb + o1);
        }
        cb ^= 1;
    }
    const int rem = len - nfull * CH;             // 0..7 remainder steps
    for (int i = 0; i < rem; ++i) step(cb, i, nfull * CH + i);

    // terminal = fv + W[END][prev]; first-max argmax via shuffle butterfly
    float tv = nf + wEnd;
    int   ti = lane;
    #pragma unroll
    for (int off = 32; off >= 1; off >>= 1) {
        const float ov = __shfl_xor(tv, off);
        const int   oi = __shfl_xor(ti, off);
        if (ov > tv || (ov == tv && oi < ti)) { tv = ov; ti = oi; }
    }
    if (lane == 0) out[b] = tv;
    const int bestlast = ti;                      // uniform across lanes

    // padding region: path[t] = bestlast for t in [len-1, T)
    for (int t = lane; t < T; t += 64)
        if (t >= len - 1) path[t] = (unsigned short)bestlast;
    __builtin_amdgcn_wave_barrier();

    // serial chase (lane 0, LDS-resident backpointers)
    if (lane == 0) {
        int tag = bestlast;
        for (int t = len - 1; t >= 1; --t) {
            tag = bptr[t * TAGS + tag];
            path[t - 1] = (unsigned short)tag;
        }
    }
    __builtin_amdgcn_wave_barrier();

    // coalesced path writeback (tags as float32)
    float* pout = out + B + (size_t)b * T;
    for (int t = lane; t < T; t += 64)
        pout[t] = (float)path[t];
}

extern "C" void kernel_launch(void* const* d_in, const int* in_sizes, int n_in,
                              void* d_out, int out_size, void* d_ws, size_t ws_size,
                              hipStream_t stream) {
    const float* feats   = (const float*)d_in[0];
    const float* weights = (const float*)d_in[1];
    const int*   lens    = (const int*)d_in[2];
    float*       out     = (float*)d_out;

    const int B = in_sizes[2];
    const int T = in_sizes[0] / (B * TAGS);

    crf_viterbi<<<dim3(B), dim3(64), 0, stream>>>(feats, weights, lens, out, B, T);
}

// Round 9
// 449.178 us; speedup vs baseline: 1.1717x; 1.1717x over previous
//
#include <hip/hip_runtime.h>

#define TAGS 64
#define MAXT 512
#define NEG  -10000.0f
#define CH   8   // feat prefetch chunk

// Round-15: split each STEP across 2 symmetric waves (halve the serial
// wave's instruction count), per-step __syncthreads.
// Model (fits r0/r1/r3): at 1 wave/SIMD a wave issues ~1 instr/4 cyc
// (issue-rotation cadence); per-step ~= 4 x serial-wave instr count.
// r7 showed 2 waves/SIMD co-issue fine (VALUBusy 53%, spare slots).
// r8 showed the allocator hard-caps ~132 VGPR: any plan with 3 live
// 64-reg arrays spills (fq_pre pipeline died of scratch).
// This split is SYMMETRIC (no producer/consumer divergence, unlike the
// voided r2/r5/r6): lane -> next n = wid*32+(lane&31), prev-half
// h = lane>>5. Per lane: 8 ds_read_b128 + 32 adds + 17-op max3 tree +
// shfl_xor(32) combine -> exact m (fmax order-free); nf = m + feat;
// argmax = 32 bitwise keys (r3-verified: key=(bits(m-c)&~63)|p, winner
// key==p, first-occurrence via min) + tree + shfl_xor(32) + min.
// ~160 instr/step vs r0's 293. VGPR ~115 (w-half 32 + quads 32 + temps).
// fv ping-pongs in fvbuf[2][64]; 1 __syncthreads/step (read cur ->
// write cur^1 -> barrier; cross-buffer => no second barrier).
__global__ __launch_bounds__(128, 1) void crf_viterbi(
    const float* __restrict__ feats,   // [B, T, K]
    const float* __restrict__ weights, // [K, K] (weights[next][prev])
    const int*   __restrict__ lens,    // [B]
    float*       __restrict__ out,     // [B] scores ++ [B*T] paths (as f32)
    int B, int T)
{
    const int b    = blockIdx.x;
    const int tid  = threadIdx.x;
    const int wid  = tid >> 6;                 // wave 0 / 1
    const int lane = tid & 63;
    const int n    = wid * 32 + (lane & 31);   // this lane's next tag
    const int h    = lane >> 5;                // prev half (0: 0-31, 1: 32-63)
    const int len  = lens[b];                  // 1..T

    __shared__ float fvbuf[2][TAGS];             // 512 B ping-pong fv
    __shared__ unsigned char  bptr[MAXT * TAGS]; // 32 KB
    __shared__ unsigned short path[MAXT];        // 1 KB
    // ~33.8 KB -> 4 blocks/CU = 8 waves/CU = 2 waves/SIMD

#define F3(a, b, c) fmaxf(fmaxf((a), (b)), (c))
#define M3(a, b, c) min(min((a), (b)), (c))

    // W half-row: W[n][h*32 + j], j = 0..31, as 8 quads (32 VGPR)
    float4 w4[8];
    #pragma unroll
    for (int g = 0; g < 8; ++g)
        w4[g] = *reinterpret_cast<const float4*>(weights + n * TAGS + h * 32 + 4 * g);
    const float wEnd = weights[1 * TAGS + lane];  // terminal, lane-indexed

    const float* fb  = feats + (size_t)b * T * TAGS;
    const int    cap = len * TAGS;

    // feat prefetch in registers (r1-verified): per-lane offset uses n
    float fcur[CH], fnx[CH];
    #pragma unroll
    for (int i = 0; i < CH; ++i) {
        int o = i * TAGS + n; if (o >= cap) o = n;
        fcur[i] = fb[o];
    }
    #pragma unroll
    for (int i = 0; i < CH; ++i) {
        int o = (CH + i) * TAGS + n; if (o >= cap) o = n;
        fnx[i] = fb[o];
    }

    if (tid < 64) fvbuf[0][lane] = (lane == 0) ? 0.0f : NEG;  // START = 0
    __syncthreads();

    int cur = 0;
    float nf = NEG;                               // this lane's running fv[n]

    auto step = [&](float feat, int t) {
        // my half's fv quads (broadcast reads, conflict-free)
        const float* fvh = &fvbuf[cur][h * 32];
        float4 c4[8];
        #pragma unroll
        for (int g = 0; g < 8; ++g) {
            const float4 fq = *reinterpret_cast<const float4*>(fvh + 4 * g);
            c4[g].x = fq.x + w4[g].x;
            c4[g].y = fq.y + w4[g].y;
            c4[g].z = fq.z + w4[g].z;
            c4[g].w = fq.w + w4[g].w;
        }
        const float* cc = reinterpret_cast<const float*>(c4);

        // max over my 32 prevs: 3-ary tree (17 ops)
        float v1[11];
        #pragma unroll
        for (int k = 0; k < 10; ++k) v1[k] = F3(cc[3*k], cc[3*k+1], cc[3*k+2]);
        v1[10] = fmaxf(cc[30], cc[31]);
        const float v20 = F3(v1[0], v1[1], v1[2]);
        const float v21 = F3(v1[3], v1[4], v1[5]);
        const float v22 = F3(v1[6], v1[7], v1[8]);
        const float v23 = fmaxf(v1[9], v1[10]);
        const float mh  = fmaxf(F3(v20, v21, v22), v23);

        // combine halves: partner lane (lane^32) has same n, other prevs
        const float mo = __shfl_xor(mh, 32);
        const float m  = fmaxf(mh, mo);           // exact full max

        nf = m + feat;                            // emission after max
        if (lane < 32) fvbuf[cur ^ 1][n] = nf;    // n == wid*32+lane here

        // bitwise first-occurrence argmax over my half (r3-verified)
        unsigned q[8];
        #pragma unroll
        for (int g = 0; g < 8; ++g) {
            const int p = h * 32 + 4 * g;
            const unsigned k0 = (__float_as_uint(m - c4[g].x) & 0xFFFFFFC0u) | (unsigned)(p + 0);
            const unsigned k1 = (__float_as_uint(m - c4[g].y) & 0xFFFFFFC0u) | (unsigned)(p + 1);
            const unsigned k2 = (__float_as_uint(m - c4[g].z) & 0xFFFFFFC0u) | (unsigned)(p + 2);
            const unsigned k3 = (__float_as_uint(m - c4[g].w) & 0xFFFFFFC0u) | (unsigned)(p + 3);
            q[g] = min(M3(k0, k1, k2), k3);
        }
        const unsigned u0 = M3(q[0], q[1], q[2]);
        const unsigned u1 = M3(q[3], q[4], q[5]);
        const unsigned u2 = min(q[6], q[7]);
        const unsigned uh = M3(u0, u1, u2);       // my half's best key
        const unsigned uo = __shfl_xor(uh, 32);
        const unsigned idx = min(uh, uo);         // global winner prev (0..63)

        if (lane < 32) bptr[t * TAGS + n] = (unsigned char)idx;

        __syncthreads();                          // publish fv(t) block-wide
        cur ^= 1;
    };

    const int nfull = len / CH;
    for (int c = 0; c < nfull; ++c) {
        #pragma unroll
        for (int i = 0; i < CH; ++i) step(fcur[i], c * CH + i);
        #pragma unroll
        for (int i = 0; i < CH; ++i) fcur[i] = fnx[i];
        #pragma unroll
        for (int i = 0; i < CH; ++i) {
            int o = (c + 2) * CH * TAGS + i * TAGS + n;
            if (o >= cap) o = n;
            fnx[i] = fb[o];
        }
    }
    const int rem = len - nfull * CH;             // 0..7 remainder steps
    #pragma unroll
    for (int i = 0; i < CH; ++i)                  // static indices
        if (i < rem) step(fcur[i], nfull * CH + i);

    if (wid != 0) return;   // wave 1 done (no barriers below)

    // final fv is in fvbuf[cur] (last write went to cur^1, then cur flipped)
    const float fvl = fvbuf[cur][lane];

    // terminal = fv + W[END][prev]; first-max argmax via shuffle butterfly
    float tv = fvl + wEnd;
    int   ti = lane;
    #pragma unroll
    for (int off = 32; off >= 1; off >>= 1) {
        const float ov = __shfl_xor(tv, off);
        const int   oi = __shfl_xor(ti, off);
        if (ov > tv || (ov == tv && oi < ti)) { tv = ov; ti = oi; }
    }
    if (lane == 0) out[b] = tv;
    const int bestlast = ti;                      // uniform across lanes

    // padding region: path[t] = bestlast for t in [len-1, T)
    for (int t = lane; t < T; t += 64)
        if (t >= len - 1) path[t] = (unsigned short)bestlast;
    __builtin_amdgcn_wave_barrier();

    // serial chase (lane 0, LDS-resident backpointers)
    if (lane == 0) {
        int tag = bestlast;
        for (int t = len - 1; t >= 1; --t) {
            tag = bptr[t * TAGS + tag];
            path[t - 1] = (unsigned short)tag;
        }
    }
    __builtin_amdgcn_wave_barrier();

    // coalesced path writeback (tags as float32)
    float* pout = out + B + (size_t)b * T;
    for (int t = lane; t < T; t += 64)
        pout[t] = (float)path[t];
}

extern "C" void kernel_launch(void* const* d_in, const int* in_sizes, int n_in,
                              void* d_out, int out_size, void* d_ws, size_t ws_size,
                              hipStream_t stream) {
    const float* feats   = (const float*)d_in[0];
    const float* weights = (const float*)d_in[1];
    const int*   lens    = (const int*)d_in[2];
    float*       out     = (float*)d_out;

    const int B = in_sizes[2];
    const int T = in_sizes[0] / (B * TAGS);

    crf_viterbi<<<dim3(B), dim3(128), 0, stream>>>(feats, weights, lens, out, B, T);
}